// Round 11
// baseline (115.322 us; speedup 1.0000x reference)
//
#include <hip/hip_runtime.h>
#include <math.h>

#define C_NUM 1000
#define M_MODES 10
#define CMTOT (C_NUM * M_MODES)   // 10000
#define D_FEAT 128
#define N_BATCH 1024

typedef _Float16 h16;
typedef h16 h16x2 __attribute__((ext_vector_type(2)));
typedef h16 half8 __attribute__((ext_vector_type(8)));
typedef float f32x4 __attribute__((ext_vector_type(4)));

// ---- workspace layout (float units) ----
#define OFF_FEATH  0              // h16[1024*128]  = 65536 floats
#define OFF_AVEH   65536          // h16[10000*128] = 640000 floats
#define OFF_CMC    705536         // float[10000*8] per-cm epilogue constants

// ---------------- P: barrier-free prep, one wave per (class,mode) ------------
// Blocks 0..2499: 4 waves, wave w handles cm = blockIdx*4+w (c=cm/10, m=cm%10).
// Blocks 2500..2755: feat -> fp16 (wave converts one of 1024 rows).
// No LDS, no barriers, no atomics: samples found by register scan + __ballot.
// cmc[cm*8+{0..5}] = { 2k, k*k+3970, sw_k, c1, c2, c3 }, sw_k=sqrt(k^2+3969);
// logit(s) = D*(c1 + D*(c2 + D*c3)),  D = (2k*s+1)/(sw_new+sw_k).
__global__ __launch_bounds__(256) void prep(
    const float* __restrict__ feat,      // [1024][128]
    const float* __restrict__ ave_old,   // [1000][10][128]
    const float* __restrict__ amount,    // [10000]
    const int*   __restrict__ labels,    // [1024]
    h16*   __restrict__ feat_h,          // [1024][128]
    h16*   __restrict__ ave_h,           // [10000][128]
    float* __restrict__ cmc)             // [10000][8]
{
    const int wave = threadIdx.x >> 6;
    const int lane = threadIdx.x & 63;
    const float2* feat2 = (const float2*)feat;
    const float2* ave2  = (const float2*)ave_old;

    if (blockIdx.x >= 2500) {            // feat -> fp16 tail blocks
        const int n = (blockIdx.x - 2500) * 4 + wave;
        float2 f = feat2[n * 64 + lane];
        ((h16x2*)(feat_h + n * D_FEAT))[lane] = (h16x2){(h16)f.x, (h16)f.y};
        return;
    }

    const int cm = blockIdx.x * 4 + wave;        // 0..9999
    const int c  = cm / M_MODES;
    const int m  = cm - c * M_MODES;

    // load my class's 10 prototype rows (float2 per lane each)
    float2 ao[M_MODES];
    #pragma unroll
    for (int j = 0; j < M_MODES; ++j) ao[j] = ave2[(c * M_MODES + j) * 64 + lane];

    // prototype norms: one fused 10-value butterfly
    float an[M_MODES];
    #pragma unroll
    for (int j = 0; j < M_MODES; ++j) an[j] = ao[j].x * ao[j].x + ao[j].y * ao[j].y;
    #pragma unroll
    for (int s = 1; s < 64; s <<= 1)
        #pragma unroll
        for (int j = 0; j < M_MODES; ++j) an[j] += __shfl_xor(an[j], s);
    #pragma unroll
    for (int j = 0; j < M_MODES; ++j) an[j] = sqrtf(an[j]);

    // scan labels from registers: lane covers n = 4*lane+256*k4+j
    float ssum = 0.f, wx = 0.f, wy = 0.f;
    const int4* lab4 = (const int4*)labels;
    #pragma unroll
    for (int k4 = 0; k4 < 4; ++k4) {
        int4 lv = lab4[lane + k4 * 64];
        #pragma unroll
        for (int j = 0; j < 4; ++j) {
            int lbl = (j == 0) ? lv.x : (j == 1) ? lv.y : (j == 2) ? lv.z : lv.w;
            unsigned long long mask = __ballot(lbl == c);
            while (mask) {
                int lz = __ffsll((long long)mask) - 1;
                mask &= mask - 1;
                const int n = 4 * lz + 256 * k4 + j;
                float2 f = feat2[n * 64 + lane];
                // fused reduce: fn + 10 dots
                float d[M_MODES], fn = f.x * f.x + f.y * f.y;
                #pragma unroll
                for (int t = 0; t < M_MODES; ++t)
                    d[t] = f.x * ao[t].x + f.y * ao[t].y;
                #pragma unroll
                for (int s = 1; s < 64; s <<= 1) {
                    fn += __shfl_xor(fn, s);
                    #pragma unroll
                    for (int t = 0; t < M_MODES; ++t) d[t] += __shfl_xor(d[t], s);
                }
                const float fnorm = sqrtf(fn);
                float sc[M_MODES], mx = -INFINITY;
                #pragma unroll
                for (int t = 0; t < M_MODES; ++t) {
                    float den = fmaxf(fnorm * an[t], 1e-8f);
                    sc[t] = d[t] / den;
                    mx = fmaxf(mx, sc[t]);
                }
                float se = 0.f;
                #pragma unroll
                for (int t = 0; t < M_MODES; ++t) { sc[t] = __expf(sc[t] - mx); se += sc[t]; }
                const float soft_m = sc[m] / se;
                ssum += soft_m;
                wx = fmaf(soft_m, f.x, wx);
                wy = fmaf(soft_m, f.y, wy);
            }
        }
    }

    // CV update for my (c,m)
    const float am = amount[cm];
    float w = ssum / (ssum + am);
    if (!(w == w)) w = 0.0f;
    const float dn = (ssum == 0.0f) ? 1.0f : ssum;

    float ax = ao[m].x * (1.0f - w) + (wx / dn) * w;
    float ay = ao[m].y * (1.0f - w) + (wy / dn) * w;

    float r2 = ax * ax + ay * ay;
    #pragma unroll
    for (int s = 1; s < 64; s <<= 1) r2 += __shfl_xor(r2, s);
    const float R = sqrtf(r2);

    float kappa = 128.0f * R / (1.0f - R * R);
    if (kappa > 1e5f || kappa < 0.0f) kappa = 1e5f;

    const float nrm = fmaxf(R, 1e-12f);
    ((h16x2*)(ave_h + cm * D_FEAT))[lane] = (h16x2){(h16)(ax / nrm), (h16)(ay / nrm)};

    if (lane == 0) {
        float k   = kappa;
        float swk = sqrtf(fmaf(k, k, 3969.0f));
        float i1  = 1.0f / (63.0f + swk);
        float i2  = 1.0f / swk;
        float c1  = 1.0f - 63.0f * i1 - 0.5f * i2;
        float c2  = 31.5f * i1 * i1 + 0.25f * i2 * i2;
        float c3  = -(21.0f * i1 * i1 * i1 + (1.0f / 6.0f) * i2 * i2 * i2);
        float4* p = (float4*)(cmc + cm * 8);
        p[0] = make_float4(2.0f * k, fmaf(k, k, 3970.0f), swk, c1);
        p[1] = make_float4(c2, c3, 0.0f, 0.0f);
    }
}

// ---------------- K3: f16 MFMA sims-GEMM + rational vMF logit + mode-max -----
// (byte-identical to round 10)
#define SWZ(row, j) (((row) << 8) + ((((j) ^ ((row) & 15))) << 4))
#define LSTR 81
__global__ __launch_bounds__(512) void k3_logits(
    const h16*   __restrict__ feat_h,    // [1024][128]
    const h16*   __restrict__ ave_h,     // [10000][128]
    const float* __restrict__ cmc,       // [10000][8]
    float* __restrict__ out)             // [1024][1000]
{
    __shared__ __align__(16) char smem[128 * 256 + 80 * 256];  // 53248 B
    char*  smemB = smem + 128 * 256;
    float* ls    = (float*)smem;          // [128][81] overlay (41472 B)

    const int tid    = threadIdx.x;
    const int cmbase = blockIdx.x * 80;   // 125 tiles, exact
    const int nbase  = blockIdx.y * 128;  // 8 tiles, exact

    {
        const float4* src = (const float4*)(feat_h + nbase * D_FEAT);
        #pragma unroll
        for (int i = 0; i < 4; ++i) {
            int e = tid + i * 512;
            int r = e >> 4, j = e & 15;
            *(float4*)(smem + SWZ(r, j)) = src[e];
        }
    }
    for (int e = tid; e < 1280; e += 512) {
        int r = e >> 4, j = e & 15;
        *(float4*)(smemB + SWZ(r, j)) = ((const float4*)(ave_h + cmbase * D_FEAT))[e];
    }
    __syncthreads();

    const int wave = tid >> 6;    // 0..7 -> n-rows wave*16..wave*16+15
    const int lane = tid & 63;
    const int lrow = lane & 15;
    const int lhi  = lane >> 4;

    f32x4 acc[5] = {};
    #pragma unroll
    for (int ks = 0; ks < 4; ++ks) {
        half8 a = *(const half8*)(smem + SWZ(wave * 16 + lrow, ks * 4 + lhi));
        #pragma unroll
        for (int t = 0; t < 5; ++t) {
            half8 b = *(const half8*)(smemB + SWZ(t * 16 + lrow, ks * 4 + lhi));
            acc[t] = __builtin_amdgcn_mfma_f32_16x16x32_f16(a, b, acc[t], 0, 0, 0);
        }
    }

    #pragma unroll
    for (int t = 0; t < 5; ++t) {
        const int cm = cmbase + t * 16 + lrow;
        float4 p0 = ((const float4*)(cmc + cm * 8))[0];
        float4 p1 = ((const float4*)(cmc + cm * 8))[1];
        #pragma unroll
        for (int r = 0; r < 4; ++r) {
            float s   = acc[t][r];
            float swn = sqrtf(fmaf(p0.x, s, p0.y));
            float num = fmaf(p0.x, s, 1.0f);
            float D   = __fdividef(num, swn + p0.z);
            acc[t][r] = D * fmaf(D, fmaf(D, p1.y, p1.x), p0.w);
        }
    }

    __syncthreads();
    #pragma unroll
    for (int t = 0; t < 5; ++t)
        #pragma unroll
        for (int r = 0; r < 4; ++r)
            ls[(wave * 16 + lhi * 4 + r) * LSTR + t * 16 + lrow] = acc[t][r];
    __syncthreads();

    #pragma unroll
    for (int rep = 0; rep < 2; ++rep) {
        int id = rep * 512 + tid;
        int q  = id >> 3;
        int cl = id & 7;
        const float* row = ls + q * LSTR + cl * 10;
        float mx = row[0];
        #pragma unroll
        for (int j = 1; j < 10; ++j) mx = fmaxf(mx, row[j]);
        out[(nbase + q) * C_NUM + blockIdx.x * 8 + cl] = mx;
    }
}

extern "C" void kernel_launch(void* const* d_in, const int* in_sizes, int n_in,
                              void* d_out, int out_size, void* d_ws, size_t ws_size,
                              hipStream_t stream) {
    const float* feat    = (const float*)d_in[0];
    const float* ave_old = (const float*)d_in[1];
    const float* amount  = (const float*)d_in[2];
    const int*   labels  = (const int*)d_in[3];
    float* out = (float*)d_out;
    float* ws  = (float*)d_ws;

    h16*   feat_h = (h16*)(ws + OFF_FEATH);
    h16*   ave_h  = (h16*)(ws + OFF_AVEH);
    float* cmc    = ws + OFF_CMC;

    prep<<<dim3(2756), dim3(256), 0, stream>>>(
        feat, ave_old, amount, labels, feat_h, ave_h, cmc);

    k3_logits<<<dim3(125, 8), dim3(512), 0, stream>>>(
        feat_h, ave_h, cmc, out);
}

// Round 12
// 100.562 us; speedup vs baseline: 1.1468x; 1.1468x over previous
//
#include <hip/hip_runtime.h>
#include <math.h>

#define C_NUM 1000
#define M_MODES 10
#define CMTOT (C_NUM * M_MODES)   // 10000
#define D_FEAT 128
#define N_BATCH 1024

typedef _Float16 h16;
typedef h16 h16x2 __attribute__((ext_vector_type(2)));
typedef h16 half8 __attribute__((ext_vector_type(8)));
typedef float f32x4 __attribute__((ext_vector_type(4)));

// ---- workspace layout (float units) ----
#define OFF_FEATH  0              // h16[1024*128]  = 65536 floats
#define OFF_AVEH   65536          // h16[10000*128] = 640000 floats
#define OFF_CMC    705536         // float[10000*8] per-cm epilogue constants

// ---------------- P: barrier-free prep, one wave per CLASS -------------------
// Blocks 0..249: 4 waves, wave w owns class c = blockIdx*4+w; handles all 10
// modes (softmax computed ONCE per sample, not 10x). All register arrays are
// indexed only by compile-time-constant unrolled indices (no scratch - rule #20).
// Blocks 250..505: feat -> fp16 conversion.
// cmc[cm*8+{0..5}] = { 2k, k*k+3970, sw_k, c1, c2, c3 }, sw_k=sqrt(k^2+3969);
// logit(s) = D*(c1 + D*(c2 + D*c3)),  D = (2k*s+1)/(sw_new+sw_k).
__global__ __launch_bounds__(256) void prep(
    const float* __restrict__ feat,      // [1024][128]
    const float* __restrict__ ave_old,   // [1000][10][128]
    const float* __restrict__ amount,    // [10000]
    const int*   __restrict__ labels,    // [1024]
    h16*   __restrict__ feat_h,          // [1024][128]
    h16*   __restrict__ ave_h,           // [10000][128]
    float* __restrict__ cmc)             // [10000][8]
{
    const int wave = threadIdx.x >> 6;
    const int lane = threadIdx.x & 63;
    const float2* feat2 = (const float2*)feat;
    const float2* ave2  = (const float2*)ave_old;

    if (blockIdx.x >= 250) {             // feat -> fp16 tail blocks
        const int n = (blockIdx.x - 250) * 4 + wave;
        float2 f = feat2[n * 64 + lane];
        ((h16x2*)(feat_h + n * D_FEAT))[lane] = (h16x2){(h16)f.x, (h16)f.y};
        return;
    }

    const int c = blockIdx.x * 4 + wave;         // class 0..999

    // load my class's 10 prototype rows (float2 per lane each)
    float2 ao[M_MODES];
    #pragma unroll
    for (int t = 0; t < M_MODES; ++t) ao[t] = ave2[(c * M_MODES + t) * 64 + lane];

    // prototype norms: one fused 10-value butterfly
    float an[M_MODES];
    #pragma unroll
    for (int t = 0; t < M_MODES; ++t) an[t] = ao[t].x * ao[t].x + ao[t].y * ao[t].y;
    #pragma unroll
    for (int s = 1; s < 64; s <<= 1)
        #pragma unroll
        for (int t = 0; t < M_MODES; ++t) an[t] += __shfl_xor(an[t], s);
    #pragma unroll
    for (int t = 0; t < M_MODES; ++t) an[t] = sqrtf(an[t]);

    // scan labels from registers; accumulate all 10 modes' weighted sums
    float ssum[M_MODES], wx[M_MODES], wy[M_MODES];
    #pragma unroll
    for (int t = 0; t < M_MODES; ++t) { ssum[t] = 0.f; wx[t] = 0.f; wy[t] = 0.f; }

    const int4* lab4 = (const int4*)labels;
    #pragma unroll
    for (int k4 = 0; k4 < 4; ++k4) {
        int4 lv = lab4[lane + k4 * 64];
        #pragma unroll
        for (int j = 0; j < 4; ++j) {
            int lbl = (j == 0) ? lv.x : (j == 1) ? lv.y : (j == 2) ? lv.z : lv.w;
            unsigned long long mask = __ballot(lbl == c);
            while (mask) {
                int lz = __ffsll((long long)mask) - 1;
                mask &= mask - 1;
                const int n = 4 * lz + 256 * k4 + j;
                float2 f = feat2[n * 64 + lane];
                float d[M_MODES], fn = f.x * f.x + f.y * f.y;
                #pragma unroll
                for (int t = 0; t < M_MODES; ++t)
                    d[t] = f.x * ao[t].x + f.y * ao[t].y;
                #pragma unroll
                for (int s = 1; s < 64; s <<= 1) {
                    fn += __shfl_xor(fn, s);
                    #pragma unroll
                    for (int t = 0; t < M_MODES; ++t) d[t] += __shfl_xor(d[t], s);
                }
                const float fnorm = sqrtf(fn);
                float sc[M_MODES], mx = -INFINITY;
                #pragma unroll
                for (int t = 0; t < M_MODES; ++t) {
                    float den = fmaxf(fnorm * an[t], 1e-8f);
                    sc[t] = d[t] / den;
                    mx = fmaxf(mx, sc[t]);
                }
                float se = 0.f;
                #pragma unroll
                for (int t = 0; t < M_MODES; ++t) { sc[t] = __expf(sc[t] - mx); se += sc[t]; }
                const float inv = 1.0f / se;
                #pragma unroll
                for (int t = 0; t < M_MODES; ++t) {
                    float sm = sc[t] * inv;
                    ssum[t] += sm;
                    wx[t] = fmaf(sm, f.x, wx[t]);
                    wy[t] = fmaf(sm, f.y, wy[t]);
                }
            }
        }
    }

    // CV update for all 10 modes; r2 butterfly fused across modes
    float r2[M_MODES];
    #pragma unroll
    for (int t = 0; t < M_MODES; ++t) {
        const float am = amount[c * M_MODES + t];     // uniform across lanes
        float w = ssum[t] / (ssum[t] + am);
        if (!(w == w)) w = 0.0f;
        const float dn = (ssum[t] == 0.0f) ? 1.0f : ssum[t];
        float ax = ao[t].x * (1.0f - w) + (wx[t] / dn) * w;
        float ay = ao[t].y * (1.0f - w) + (wy[t] / dn) * w;
        ao[t].x = ax; ao[t].y = ay;                   // reuse registers
        r2[t] = ax * ax + ay * ay;
    }
    #pragma unroll
    for (int s = 1; s < 64; s <<= 1)
        #pragma unroll
        for (int t = 0; t < M_MODES; ++t) r2[t] += __shfl_xor(r2[t], s);

    // normalized fp16 prototypes (all lanes; nrm recomputed per mode)
    #pragma unroll
    for (int t = 0; t < M_MODES; ++t) {
        const float R   = sqrtf(r2[t]);
        const float nrm = fmaxf(R, 1e-12f);
        ((h16x2*)(ave_h + (c * M_MODES + t) * D_FEAT))[lane] =
            (h16x2){(h16)(ao[t].x / nrm), (h16)(ao[t].y / nrm)};
    }

    // kappa + cmc constants: lane t handles mode t (select chain, no scratch)
    if (lane < M_MODES) {
        float myr2 = 0.f;
        #pragma unroll
        for (int t = 0; t < M_MODES; ++t) if (lane == t) myr2 = r2[t];
        const float R = sqrtf(myr2);
        float kappa = 128.0f * R / (1.0f - R * R);
        if (kappa > 1e5f || kappa < 0.0f) kappa = 1e5f;
        float k   = kappa;
        float swk = sqrtf(fmaf(k, k, 3969.0f));
        float i1  = 1.0f / (63.0f + swk);
        float i2  = 1.0f / swk;
        float c1  = 1.0f - 63.0f * i1 - 0.5f * i2;
        float c2  = 31.5f * i1 * i1 + 0.25f * i2 * i2;
        float c3  = -(21.0f * i1 * i1 * i1 + (1.0f / 6.0f) * i2 * i2 * i2);
        float4* p = (float4*)(cmc + (c * M_MODES + lane) * 8);
        p[0] = make_float4(2.0f * k, fmaf(k, k, 3970.0f), swk, c1);
        p[1] = make_float4(c2, c3, 0.0f, 0.0f);
    }
}

// ---------------- K3: f16 MFMA sims-GEMM + rational vMF logit + mode-max -----
// (byte-identical to round 10)
#define SWZ(row, j) (((row) << 8) + ((((j) ^ ((row) & 15))) << 4))
#define LSTR 81
__global__ __launch_bounds__(512) void k3_logits(
    const h16*   __restrict__ feat_h,    // [1024][128]
    const h16*   __restrict__ ave_h,     // [10000][128]
    const float* __restrict__ cmc,       // [10000][8]
    float* __restrict__ out)             // [1024][1000]
{
    __shared__ __align__(16) char smem[128 * 256 + 80 * 256];  // 53248 B
    char*  smemB = smem + 128 * 256;
    float* ls    = (float*)smem;          // [128][81] overlay (41472 B)

    const int tid    = threadIdx.x;
    const int cmbase = blockIdx.x * 80;   // 125 tiles, exact
    const int nbase  = blockIdx.y * 128;  // 8 tiles, exact

    {
        const float4* src = (const float4*)(feat_h + nbase * D_FEAT);
        #pragma unroll
        for (int i = 0; i < 4; ++i) {
            int e = tid + i * 512;
            int r = e >> 4, j = e & 15;
            *(float4*)(smem + SWZ(r, j)) = src[e];
        }
    }
    for (int e = tid; e < 1280; e += 512) {
        int r = e >> 4, j = e & 15;
        *(float4*)(smemB + SWZ(r, j)) = ((const float4*)(ave_h + cmbase * D_FEAT))[e];
    }
    __syncthreads();

    const int wave = tid >> 6;    // 0..7 -> n-rows wave*16..wave*16+15
    const int lane = tid & 63;
    const int lrow = lane & 15;
    const int lhi  = lane >> 4;

    f32x4 acc[5] = {};
    #pragma unroll
    for (int ks = 0; ks < 4; ++ks) {
        half8 a = *(const half8*)(smem + SWZ(wave * 16 + lrow, ks * 4 + lhi));
        #pragma unroll
        for (int t = 0; t < 5; ++t) {
            half8 b = *(const half8*)(smemB + SWZ(t * 16 + lrow, ks * 4 + lhi));
            acc[t] = __builtin_amdgcn_mfma_f32_16x16x32_f16(a, b, acc[t], 0, 0, 0);
        }
    }

    #pragma unroll
    for (int t = 0; t < 5; ++t) {
        const int cm = cmbase + t * 16 + lrow;
        float4 p0 = ((const float4*)(cmc + cm * 8))[0];
        float4 p1 = ((const float4*)(cmc + cm * 8))[1];
        #pragma unroll
        for (int r = 0; r < 4; ++r) {
            float s   = acc[t][r];
            float swn = sqrtf(fmaf(p0.x, s, p0.y));
            float num = fmaf(p0.x, s, 1.0f);
            float D   = __fdividef(num, swn + p0.z);
            acc[t][r] = D * fmaf(D, fmaf(D, p1.y, p1.x), p0.w);
        }
    }

    __syncthreads();
    #pragma unroll
    for (int t = 0; t < 5; ++t)
        #pragma unroll
        for (int r = 0; r < 4; ++r)
            ls[(wave * 16 + lhi * 4 + r) * LSTR + t * 16 + lrow] = acc[t][r];
    __syncthreads();

    #pragma unroll
    for (int rep = 0; rep < 2; ++rep) {
        int id = rep * 512 + tid;
        int q  = id >> 3;
        int cl = id & 7;
        const float* row = ls + q * LSTR + cl * 10;
        float mx = row[0];
        #pragma unroll
        for (int j = 1; j < 10; ++j) mx = fmaxf(mx, row[j]);
        out[(nbase + q) * C_NUM + blockIdx.x * 8 + cl] = mx;
    }
}

extern "C" void kernel_launch(void* const* d_in, const int* in_sizes, int n_in,
                              void* d_out, int out_size, void* d_ws, size_t ws_size,
                              hipStream_t stream) {
    const float* feat    = (const float*)d_in[0];
    const float* ave_old = (const float*)d_in[1];
    const float* amount  = (const float*)d_in[2];
    const int*   labels  = (const int*)d_in[3];
    float* out = (float*)d_out;
    float* ws  = (float*)d_ws;

    h16*   feat_h = (h16*)(ws + OFF_FEATH);
    h16*   ave_h  = (h16*)(ws + OFF_AVEH);
    float* cmc    = ws + OFF_CMC;

    prep<<<dim3(506), dim3(256), 0, stream>>>(
        feat, ave_old, amount, labels, feat_h, ave_h, cmc);

    k3_logits<<<dim3(125, 8), dim3(512), 0, stream>>>(
        feat_h, ave_h, cmc, out);
}